// Round 2
// baseline (251.304 us; speedup 1.0000x reference)
//
#include <hip/hip_runtime.h>
#include <math.h>

#define N_ENTC 30000
#define ALL_RELC 221
#define NDIM 32
#define EVAL_RELC 86
#define BB 16
#define NE 120000
#define ROW 512            /* BB*NDIM floats per entity row */
#define NSCAN 120          /* scan stripes; NSCAN*EPB == NE */
#define EPB 1000
#define MW 938             /* bitmask words for 30000 entities */

// Two regular (graph-capturable) dispatches; stream order is the only barrier.
//  K1 k_scan : 120 blocks. Records per stripe (R6-proven packed int4 format),
//              counts, idempotent zero of hidB rows for L2-record heads,
//              block0: relw -> global, block1: zero qacc.   [round-0 proven]
//  K2 k_rest : 1 block, 512 threads. Everything else:
//              msg1 (waves 0-3: d=0, waves 4-7: d=1; disjoint hidB halves)
//              -> __syncthreads ->
//              lin1+msg2 fused in registers (hidC eliminated; round-1 proven)
//              -> __syncthreads ->
//              fin: layer-2 linear + gather + output GEMM (round-1 proven).

__global__ __launch_bounds__(512) void k_scan(
    const int* __restrict__ head, const int* __restrict__ tail,
    const int* __restrict__ eh, const int* __restrict__ et,
    const int* __restrict__ er, const float* __restrict__ ew,
    const float* __restrict__ ent_emb,
    const float* __restrict__ Wrel, const float* __restrict__ brel,
    const float* __restrict__ Watt, const float* __restrict__ batt,
    int4* __restrict__ recs, int* __restrict__ counts,
    float* __restrict__ relwG, float* __restrict__ hidB,
    float* __restrict__ qaccB)
{
    __shared__ unsigned mH[MW], mT[MW];
    __shared__ int s_src[32];
    __shared__ int s_cnt[4];
    __shared__ float s_ht[BB * 64];
    __shared__ float s_h5[BB * 5];
    const int t = threadIdx.x, bid = blockIdx.x;

    if (t < 32) s_src[t] = (t < BB) ? head[t] : tail[t - BB];
    for (int i = t; i < MW; i += 512) { mH[i] = 0u; mT[i] = 0u; }
    if (t < 4) s_cnt[t] = 0;
    __syncthreads();
    if (t < BB) {
        int h = s_src[t], q = s_src[BB + t];
        atomicOr(&mH[h >> 5], 1u << (h & 31));
        atomicOr(&mT[q >> 5], 1u << (q & 31));
    }
    __syncthreads();

    const int e0 = bid * EPB;
    const int4* eh4 = (const int4*)(eh + e0);
    const int4* et4 = (const int4*)(et + e0);
    for (int p = t; p < EPB / 4; p += 512) {
        int4 h4 = eh4[p], t4 = et4[p];
        int hv[4] = {h4.x, h4.y, h4.z, h4.w};
        int tv[4] = {t4.x, t4.y, t4.z, t4.w};
#pragma unroll
        for (int c = 0; c < 4; c++) {
            int e = e0 + 4 * p + c, h = hv[c], tt = tv[c];
            bool hH = (mH[h >> 5] >> (h & 31)) & 1u;
            bool hT = (mT[h >> 5] >> (h & 31)) & 1u;
            bool tT = (mT[tt >> 5] >> (tt & 31)) & 1u;
            bool tH = (mH[tt >> 5] >> (tt & 31)) & 1u;
            if (!(hH | hT | tT | tH)) continue;
            int r = er[e];
            int wb = __float_as_int(ew[e]);
            if (hH) { // d=0 layer-1: srcmask over head ids
                unsigned m = 0;
#pragma unroll
                for (int b = 0; b < BB; b++) m |= (s_src[b] == h) ? (1u << b) : 0u;
                int pos = atomicAdd(&s_cnt[0], 1);
                recs[(size_t)bid * EPB + pos] = make_int4(tt, r | (int)(m << 8), wb, h);
            }
            if (hT) { // d=1 layer-1: srcmask over tail ids
                unsigned m = 0;
#pragma unroll
                for (int b = 0; b < BB; b++) m |= (s_src[BB + b] == h) ? (1u << b) : 0u;
                int pos = atomicAdd(&s_cnt[1], 1);
                recs[(size_t)NE + bid * EPB + pos] = make_int4(tt, r | (int)(m << 8), wb, h);
            }
            if (tT) { // d=0 layer-2: canon = first matching tail slot
                unsigned m = 0;
#pragma unroll
                for (int b = 0; b < BB; b++) m |= (s_src[BB + b] == tt) ? (1u << b) : 0u;
                int canon = __ffs(m) - 1;
                int pos = atomicAdd(&s_cnt[2], 1);
                recs[(size_t)2 * NE + bid * EPB + pos] = make_int4(h, r | (canon << 8), wb, tt);
            }
            if (tH) { // d=1 layer-2: canon = first matching head slot
                unsigned m = 0;
#pragma unroll
                for (int b = 0; b < BB; b++) m |= (s_src[b] == tt) ? (1u << b) : 0u;
                int canon = __ffs(m) - 1;
                int pos = atomicAdd(&s_cnt[3], 1);
                recs[(size_t)3 * NE + bid * EPB + pos] = make_int4(h, r | (canon << 8), wb, tt);
            }
        }
    }
    __syncthreads();
    if (t < 4) counts[bid * 4 + t] = s_cnt[t];

    // Idempotent zero of hidB rows for this stripe's L2-record heads.
    {
        const int wid8 = t >> 6, lane = t & 63;
        float4 z = make_float4(0.f, 0.f, 0.f, 0.f);
        for (int li = 2; li < 4; li++) {
            int c = s_cnt[li];
            float* hb = hidB + (size_t)(li - 2) * N_ENTC * ROW;
            for (int j = wid8; j < c; j += 8) {
                int row = recs[(size_t)li * NE + bid * EPB + j].x;
                float4* p = (float4*)(hb + (size_t)row * ROW);
                p[lane] = z;
                p[lane + 64] = z;
            }
        }
    }

    if (bid == 1) { // zero qacc (both directions)
        for (int i = t; i < 2 * BB * ROW; i += 512) qaccB[i] = 0.f;
    }
    if (bid == 0) { // relation-attention weights -> global (R6-proven math)
        for (int i = t; i < BB * NDIM; i += 512) {
            int b = i >> 5, k = i & 31;
            s_ht[b * 64 + k] = ent_emb[(size_t)s_src[b] * NDIM + k];
            s_ht[b * 64 + 32 + k] = ent_emb[(size_t)s_src[BB + b] * NDIM + k];
        }
        __syncthreads();
        for (int l = 0; l < 2; l++) {
            for (int i = t; i < BB * 5; i += 512) {
                int b = i / 5, j = i % 5;
                float s = brel[l * 5 + j];
                for (int k = 0; k < 64; k++)
                    s += s_ht[b * 64 + k] * Wrel[l * 320 + k * 5 + j];
                s_h5[i] = fmaxf(s, 0.f);
            }
            __syncthreads();
            for (int i = t; i < BB * ALL_RELC; i += 512) {
                int b = i / ALL_RELC, r = i % ALL_RELC;
                float s = batt[l * ALL_RELC + r];
                for (int j = 0; j < 5; j++)
                    s += s_h5[b * 5 + j] * Watt[l * 5 * ALL_RELC + j * ALL_RELC + r];
                relwG[l * BB * ALL_RELC + i] = 1.0f / (1.0f + expf(-s));
            }
            __syncthreads();
        }
    }
}

__global__ __launch_bounds__(512) void k_rest(
    const int* __restrict__ head, const int* __restrict__ tail,
    const float* __restrict__ ent_emb, const float* __restrict__ rel_embs,
    const float* __restrict__ Wlin, const float* __restrict__ blin,
    const float* __restrict__ Wr, const float* __restrict__ br,
    const int4* __restrict__ recs, const int* __restrict__ counts,
    const float* __restrict__ relwG, float* __restrict__ hidB,
    float* __restrict__ qaccB, float* __restrict__ out)
{
    __shared__ int s_src[32];
    __shared__ int s_cnt[NSCAN][4];
    __shared__ float sW[NDIM * NDIM];
    __shared__ float sb[NDIM];
    __shared__ float sx[BB * 128]; // hemb|temb|head_hid|tail_hid
    __shared__ int s_canon[2][BB];
    const int t = threadIdx.x;

    if (t < 32) s_src[t] = (t < BB) ? head[t] : tail[t - BB];
    for (int i = t; i < NSCAN * 4; i += 512) ((int*)s_cnt)[i] = counts[i];
    for (int i = t; i < NDIM * NDIM; i += 512) sW[i] = Wlin[i]; // layer 0
    if (t < NDIM) sb[t] = blin[t];
    __syncthreads();

    const int wid = t >> 6, lane = t & 63;
    const int d = wid >> 2, w4 = wid & 3; // waves 0-3: d=0, waves 4-7: d=1

    // ============ phase B: msg1 (layer-1 messages) ============
    {
        const float4* rv0 = (const float4*)rel_embs;
        float* hb = hidB + (size_t)d * N_ENTC * ROW;
        for (int s = 0; s < NSCAN; s++) {
            int c = s_cnt[s][d];
            if (c == 0) continue;
            const int4* R = recs + (size_t)d * NE + (size_t)s * EPB;
            for (int j = w4; j < c; j += 4) {
                int4 rec = R[j];
                int tt = rec.x, r = rec.y & 255;
                unsigned msk = ((unsigned)rec.y) >> 8;
                float w = __int_as_float(rec.z);
                float* drow = hb + (size_t)tt * ROW;
#pragma unroll
                for (int ii = 0; ii < 2; ii++) {
                    int i4 = lane + 64 * ii, b = i4 >> 3, kq = i4 & 7;
                    if (!((msk >> b) & 1u)) continue;
                    float cf = relwG[b * ALL_RELC + r] * w;
                    float4 sv = ((const float4*)(ent_emb + (size_t)s_src[d * BB + b] * NDIM))[kq];
                    float4 rr = rv0[r * 8 + kq];
                    atomicAdd(drow + i4 * 4 + 0, sv.x * cf * rr.x);
                    atomicAdd(drow + i4 * 4 + 1, sv.y * cf * rr.y);
                    atomicAdd(drow + i4 * 4 + 2, sv.z * cf * rr.z);
                    atomicAdd(drow + i4 * 4 + 3, sv.w * cf * rr.w);
                }
            }
        }
    }

    __syncthreads(); // all msg1 atomics (same block) visible before row reads

    // ============ phase C: lin1 + msg2 fused (hidC eliminated) ============
    {
        const int b0 = lane >> 3, kq = lane & 7, j0 = kq * 4;
        const float4* rv1 = (const float4*)(rel_embs + (size_t)ALL_RELC * NDIM);
        const float* hb = hidB + (size_t)d * N_ENTC * ROW;
        float* qa = qaccB + (size_t)d * BB * ROW;
        for (int s = 0; s < NSCAN; s++) {
            int c = s_cnt[s][2 + d];
            if (c == 0) continue;
            const int4* R = recs + (size_t)(2 + d) * NE + (size_t)s * EPB;
            for (int j = w4; j < c; j += 4) {
                int4 rec = R[j];
                int row = rec.x, r = rec.y & 255, canon = (rec.y >> 8) & 15;
                float w = __int_as_float(rec.z);
                float4 rr = rv1[r * 8 + kq];
#pragma unroll
                for (int half = 0; half < 2; half++) {
                    int b = b0 + 8 * half;
                    const float4* src = (const float4*)(hb + (size_t)row * ROW + b * NDIM);
                    float h[NDIM];
#pragma unroll
                    for (int q = 0; q < 8; q++) {
                        float4 v = src[q];
                        h[q * 4 + 0] = v.x; h[q * 4 + 1] = v.y;
                        h[q * 4 + 2] = v.z; h[q * 4 + 3] = v.w;
                    }
                    float a0 = sb[j0], a1 = sb[j0 + 1], a2 = sb[j0 + 2], a3 = sb[j0 + 3];
#pragma unroll
                    for (int k = 0; k < NDIM; k++) {
                        float hk = h[k];
                        float4 wv = *(const float4*)&sW[k * NDIM + j0];
                        a0 += hk * wv.x; a1 += hk * wv.y;
                        a2 += hk * wv.z; a3 += hk * wv.w;
                    }
                    float cf = relwG[BB * ALL_RELC + b * ALL_RELC + r] * w;
                    float* dst = qa + canon * ROW + b * NDIM + j0;
                    atomicAdd(dst + 0, fmaxf(a0, 0.f) * cf * rr.x);
                    atomicAdd(dst + 1, fmaxf(a1, 0.f) * cf * rr.y);
                    atomicAdd(dst + 2, fmaxf(a2, 0.f) * cf * rr.z);
                    atomicAdd(dst + 3, fmaxf(a3, 0.f) * cf * rr.w);
                }
            }
        }
    }

    __syncthreads(); // all qacc atomics done; safe to overwrite sW/sb

    // ================= phase D: fin =================
    for (int i = t; i < NDIM * NDIM; i += 512) sW[i] = Wlin[NDIM * NDIM + i]; // layer 1
    if (t < NDIM) sb[t] = blin[NDIM + t];
    if (t < 2 * BB) {
        int dd = t >> 4, b = t & 15;
        int q = s_src[(1 - dd) * BB + b];
        int c = 0;
        for (int bb = 0; bb < BB; bb++)
            if (s_src[(1 - dd) * BB + bb] == q) { c = bb; break; }
        s_canon[dd][b] = c;
    }
    {
        int b = t >> 5, k = t & 31;
        sx[b * 128 + k] = ent_emb[(size_t)s_src[b] * NDIM + k];           // hemb
        sx[b * 128 + 32 + k] = ent_emb[(size_t)s_src[BB + b] * NDIM + k]; // temb
    }
    __syncthreads();
    for (int dd = 0; dd < 2; dd++) { // layer-2 linear on (canon,b) segments
        int b = t >> 5, j = t & 31;
        const float* hrow = qaccB + (size_t)dd * BB * ROW + s_canon[dd][b] * ROW + b * NDIM;
        float s = sb[j];
        for (int k = 0; k < NDIM; k++)
            s += hrow[k] * sW[k * NDIM + j];
        // d=0 (init=head, query=tail) -> tail_hid (col 96); d=1 -> head_hid (col 64)
        sx[b * 128 + (dd == 0 ? 96 : 64) + j] = fmaxf(s, 0.f);
    }
    __syncthreads();
    for (int o = t; o < BB * EVAL_RELC; o += 512) {
        int b = o / EVAL_RELC, r = o % EVAL_RELC;
        float s = br[r];
        for (int k = 0; k < 128; k++)
            s += sx[b * 128 + k] * Wr[k * EVAL_RELC + r];
        out[o] = s;
    }
}

extern "C" void kernel_launch(void* const* d_in, const int* in_sizes, int n_in,
                              void* d_out, int out_size, void* d_ws,
                              size_t ws_size, hipStream_t stream)
{
    const int* head = (const int*)d_in[0];
    const int* tail = (const int*)d_in[1];
    const int* eh = (const int*)d_in[2];
    const int* et = (const int*)d_in[3];
    const int* er = (const int*)d_in[4];
    const float* ew = (const float*)d_in[5];
    const float* ent_emb = (const float*)d_in[6];
    const float* rel_embs = (const float*)d_in[7];
    const float* Wlin = (const float*)d_in[8];
    const float* blin = (const float*)d_in[9];
    const float* Wrel = (const float*)d_in[10];
    const float* brel = (const float*)d_in[11];
    const float* Watt = (const float*)d_in[12];
    const float* batt = (const float*)d_in[13];
    const float* Wr = (const float*)d_in[14];
    const float* br = (const float*)d_in[15];
    float* out = (float*)d_out;
    float* ws = (float*)d_ws;

    // ---- workspace carve (~131 MB; hidC eliminated) ----
    float* hidB = ws;                                      // [2][N][ROW]
    int4* recs = (int4*)(hidB + (size_t)2 * N_ENTC * ROW); // [4][NE] int4
    int* counts = (int*)(recs + (size_t)4 * NE);           // [NSCAN][4]
    float* relwG = (float*)(counts + 4 * NSCAN);           // 7072 floats
    float* qaccB = relwG + 2 * BB * ALL_RELC;              // [2][16][512]

    k_scan<<<NSCAN, 512, 0, stream>>>(head, tail, eh, et, er, ew, ent_emb,
                                      Wrel, brel, Watt, batt,
                                      recs, counts, relwG, hidB, qaccB);
    k_rest<<<1, 512, 0, stream>>>(head, tail, ent_emb, rel_embs, Wlin, blin,
                                  Wr, br, recs, counts, relwG, hidB, qaccB, out);
}

// Round 3
// 128.997 us; speedup vs baseline: 1.9481x; 1.9481x over previous
//
#include <hip/hip_runtime.h>
#include <math.h>

#define N_ENTC 30000
#define ALL_RELC 221
#define NDIM 32
#define EVAL_RELC 86
#define BB 16
#define NE 120000
#define ROW 512            /* BB*NDIM floats per qacc row */
#define NSCAN 120          /* scan stripes; NSCAN*EPB == NE */
#define EPB 1000
#define MW 938             /* bitmask words for 30000 entities */
#define MAXM 512           /* match-list capacity per L2 record */

// Two regular (graph-capturable) dispatches. hidB (123 MB) eliminated:
//  K1 k_scan   : 120 blocks. Records per stripe (proven packed int4 format),
//                counts, block0: relw -> global, block1: zero qacc + done.
//  K2 k_gather : 120 blocks. Block s: for each of its L2 records (h,r,canon,w,d):
//                GATHER all L1-d records with target==h (scan via LDS counts,
//                recs region is L2-hot), build pre[b][k] in LDS (same sums as
//                the proven msg1 scatter), lin1 in registers, msg2 atomics
//                into qacc. Then threadfence + done-counter; LAST block runs
//                fin (proven body: layer-2 linear + gather + output GEMM).

__global__ __launch_bounds__(512) void k_scan(
    const int* __restrict__ head, const int* __restrict__ tail,
    const int* __restrict__ eh, const int* __restrict__ et,
    const int* __restrict__ er, const float* __restrict__ ew,
    const float* __restrict__ ent_emb,
    const float* __restrict__ Wrel, const float* __restrict__ brel,
    const float* __restrict__ Watt, const float* __restrict__ batt,
    int4* __restrict__ recs, int* __restrict__ counts,
    float* __restrict__ relwG, float* __restrict__ qaccB,
    int* __restrict__ done)
{
    __shared__ unsigned mH[MW], mT[MW];
    __shared__ int s_src[32];
    __shared__ int s_cnt[4];
    __shared__ float s_ht[BB * 64];
    __shared__ float s_h5[BB * 5];
    const int t = threadIdx.x, bid = blockIdx.x;

    if (t < 32) s_src[t] = (t < BB) ? head[t] : tail[t - BB];
    for (int i = t; i < MW; i += 512) { mH[i] = 0u; mT[i] = 0u; }
    if (t < 4) s_cnt[t] = 0;
    __syncthreads();
    if (t < BB) {
        int h = s_src[t], q = s_src[BB + t];
        atomicOr(&mH[h >> 5], 1u << (h & 31));
        atomicOr(&mT[q >> 5], 1u << (q & 31));
    }
    __syncthreads();

    const int e0 = bid * EPB;
    const int4* eh4 = (const int4*)(eh + e0);
    const int4* et4 = (const int4*)(et + e0);
    for (int p = t; p < EPB / 4; p += 512) {
        int4 h4 = eh4[p], t4 = et4[p];
        int hv[4] = {h4.x, h4.y, h4.z, h4.w};
        int tv[4] = {t4.x, t4.y, t4.z, t4.w};
#pragma unroll
        for (int c = 0; c < 4; c++) {
            int e = e0 + 4 * p + c, h = hv[c], tt = tv[c];
            bool hH = (mH[h >> 5] >> (h & 31)) & 1u;
            bool hT = (mT[h >> 5] >> (h & 31)) & 1u;
            bool tT = (mT[tt >> 5] >> (tt & 31)) & 1u;
            bool tH = (mH[tt >> 5] >> (tt & 31)) & 1u;
            if (!(hH | hT | tT | tH)) continue;
            int r = er[e];
            int wb = __float_as_int(ew[e]);
            if (hH) { // d=0 layer-1: srcmask over head ids
                unsigned m = 0;
#pragma unroll
                for (int b = 0; b < BB; b++) m |= (s_src[b] == h) ? (1u << b) : 0u;
                int pos = atomicAdd(&s_cnt[0], 1);
                recs[(size_t)bid * EPB + pos] = make_int4(tt, r | (int)(m << 8), wb, h);
            }
            if (hT) { // d=1 layer-1: srcmask over tail ids
                unsigned m = 0;
#pragma unroll
                for (int b = 0; b < BB; b++) m |= (s_src[BB + b] == h) ? (1u << b) : 0u;
                int pos = atomicAdd(&s_cnt[1], 1);
                recs[(size_t)NE + bid * EPB + pos] = make_int4(tt, r | (int)(m << 8), wb, h);
            }
            if (tT) { // d=0 layer-2: canon = first matching tail slot
                unsigned m = 0;
#pragma unroll
                for (int b = 0; b < BB; b++) m |= (s_src[BB + b] == tt) ? (1u << b) : 0u;
                int canon = __ffs(m) - 1;
                int pos = atomicAdd(&s_cnt[2], 1);
                recs[(size_t)2 * NE + bid * EPB + pos] = make_int4(h, r | (canon << 8), wb, tt);
            }
            if (tH) { // d=1 layer-2: canon = first matching head slot
                unsigned m = 0;
#pragma unroll
                for (int b = 0; b < BB; b++) m |= (s_src[b] == tt) ? (1u << b) : 0u;
                int canon = __ffs(m) - 1;
                int pos = atomicAdd(&s_cnt[3], 1);
                recs[(size_t)3 * NE + bid * EPB + pos] = make_int4(h, r | (canon << 8), wb, tt);
            }
        }
    }
    __syncthreads();
    if (t < 4) counts[bid * 4 + t] = s_cnt[t];

    if (bid == 1) { // zero qacc (both directions) + done counter
        for (int i = t; i < 2 * BB * ROW; i += 512) qaccB[i] = 0.f;
        if (t == 0) *done = 0;
    }
    if (bid == 0) { // relation-attention weights -> global (proven math)
        for (int i = t; i < BB * NDIM; i += 512) {
            int b = i >> 5, k = i & 31;
            s_ht[b * 64 + k] = ent_emb[(size_t)s_src[b] * NDIM + k];
            s_ht[b * 64 + 32 + k] = ent_emb[(size_t)s_src[BB + b] * NDIM + k];
        }
        __syncthreads();
        for (int l = 0; l < 2; l++) {
            for (int i = t; i < BB * 5; i += 512) {
                int b = i / 5, j = i % 5;
                float s = brel[l * 5 + j];
                for (int k = 0; k < 64; k++)
                    s += s_ht[b * 64 + k] * Wrel[l * 320 + k * 5 + j];
                s_h5[i] = fmaxf(s, 0.f);
            }
            __syncthreads();
            for (int i = t; i < BB * ALL_RELC; i += 512) {
                int b = i / ALL_RELC, r = i % ALL_RELC;
                float s = batt[l * ALL_RELC + r];
                for (int j = 0; j < 5; j++)
                    s += s_h5[b * 5 + j] * Watt[l * 5 * ALL_RELC + j * ALL_RELC + r];
                relwG[l * BB * ALL_RELC + i] = 1.0f / (1.0f + expf(-s));
            }
            __syncthreads();
        }
    }
}

__global__ __launch_bounds__(512) void k_gather(
    const int* __restrict__ head, const int* __restrict__ tail,
    const float* __restrict__ ent_emb, const float* __restrict__ rel_embs,
    const float* __restrict__ Wlin, const float* __restrict__ blin,
    const float* __restrict__ Wr, const float* __restrict__ br,
    const int4* __restrict__ recs, const int* __restrict__ counts,
    const float* __restrict__ relwG, float* __restrict__ qaccB,
    int* __restrict__ done, float* __restrict__ out)
{
    __shared__ int s_src[32];
    __shared__ int s_cnt[NSCAN * 4];
    __shared__ float sW[NDIM * NDIM];
    __shared__ float sb[NDIM];
    __shared__ float s_pre[BB][NDIM];
    __shared__ int2 s_match[MAXM];
    __shared__ int s_mcnt;
    __shared__ int s_last;
    __shared__ float sx[BB * 128]; // hemb|temb|head_hid|tail_hid (fin)
    __shared__ int s_canon[2][BB];
    const int t = threadIdx.x, bid = blockIdx.x;

    if (t < 32) s_src[t] = (t < BB) ? head[t] : tail[t - BB];
    for (int i = t; i < NSCAN * 4; i += 512) s_cnt[i] = counts[i];
    for (int i = t; i < NDIM * NDIM; i += 512) sW[i] = Wlin[i]; // layer 0
    if (t < NDIM) sb[t] = blin[t];
    __syncthreads();

    const int wid = t >> 6, lane = t & 63;
    const float* rel1 = rel_embs + (size_t)ALL_RELC * NDIM;

    // ===== per-stripe L2 records: gather L1 -> pre -> lin1 -> msg2 =====
    for (int d = 0; d < 2; d++) {
        int cL2 = s_cnt[bid * 4 + 2 + d];
        for (int j = 0; j < cL2; j++) {
            int4 rec = recs[(size_t)(2 + d) * NE + (size_t)bid * EPB + j];
            const int hrow = rec.x, r = rec.y & 255, canon = (rec.y >> 8) & 15;
            const float w = __int_as_float(rec.z);
            if (t == 0) s_mcnt = 0;
            __syncthreads();
            // scan all stripes' L1-d records for target == hrow
            for (int ss = wid; ss < NSCAN; ss += 8) {
                int c1 = s_cnt[ss * 4 + d];
                for (int q = lane; q < c1; q += 64) {
                    int4 lr = recs[(size_t)d * NE + (size_t)ss * EPB + q];
                    if (lr.x == hrow) {
                        int pos = atomicAdd(&s_mcnt, 1);
                        if (pos < MAXM) s_match[pos] = make_int2(lr.y, lr.z);
                    }
                }
            }
            __syncthreads();
            int mc = min(s_mcnt, MAXM);
            { // pre[b][k] = sum of matched layer-1 messages (== proven msg1 sums)
                int b = t >> 5, k = t & 31;
                float ek = ent_emb[(size_t)s_src[d * BB + b] * NDIM + k];
                float acc = 0.f;
                for (int m = 0; m < mc; m++) {
                    int2 mr = s_match[m];
                    unsigned msk = ((unsigned)mr.x) >> 8;
                    if (!((msk >> b) & 1u)) continue;
                    int rr = mr.x & 255;
                    float cf = relwG[b * ALL_RELC + rr] * __int_as_float(mr.y);
                    acc += cf * ek * rel_embs[rr * NDIM + k];
                }
                s_pre[b][k] = acc;
            }
            __syncthreads();
            { // lin1 (relu) + layer-2 message into qacc[canon]
                int b = t >> 5, jj = t & 31;
                float acc = sb[jj];
                for (int k = 0; k < NDIM; k++)
                    acc += s_pre[b][k] * sW[k * NDIM + jj];
                float cf = relwG[BB * ALL_RELC + b * ALL_RELC + r] * w;
                float v = fmaxf(acc, 0.f) * cf * rel1[r * NDIM + jj];
                atomicAdd(qaccB + (size_t)d * BB * ROW + canon * ROW + b * NDIM + jj, v);
            }
            __syncthreads(); // s_match/s_pre reused next record
        }
    }

    // ===== last-block fin =====
    __threadfence(); // my qacc atomics visible before counter bump
    if (t == 0) {
        int old = atomicAdd(done, 1);
        s_last = (old == NSCAN - 1) ? 1 : 0;
    }
    __syncthreads();
    if (!s_last) return;
    __threadfence(); // acquire: all other blocks' qacc atomics

    for (int i = t; i < NDIM * NDIM; i += 512) sW[i] = Wlin[NDIM * NDIM + i]; // layer 1
    if (t < NDIM) sb[t] = blin[NDIM + t];
    if (t < 2 * BB) {
        int dd = t >> 4, b = t & 15;
        int q = s_src[(1 - dd) * BB + b];
        int c = 0;
        for (int bb = 0; bb < BB; bb++)
            if (s_src[(1 - dd) * BB + bb] == q) { c = bb; break; }
        s_canon[dd][b] = c;
    }
    {
        int b = t >> 5, k = t & 31;
        sx[b * 128 + k] = ent_emb[(size_t)s_src[b] * NDIM + k];           // hemb
        sx[b * 128 + 32 + k] = ent_emb[(size_t)s_src[BB + b] * NDIM + k]; // temb
    }
    __syncthreads();
    for (int dd = 0; dd < 2; dd++) { // layer-2 linear on (canon,b) segments
        int b = t >> 5, j = t & 31;
        const float* hrow = qaccB + (size_t)dd * BB * ROW + s_canon[dd][b] * ROW + b * NDIM;
        float s = sb[j];
        for (int k = 0; k < NDIM; k++)
            s += hrow[k] * sW[k * NDIM + j];
        // d=0 (init=head, query=tail) -> tail_hid (col 96); d=1 -> head_hid (col 64)
        sx[b * 128 + (dd == 0 ? 96 : 64) + j] = fmaxf(s, 0.f);
    }
    __syncthreads();
    for (int o = t; o < BB * EVAL_RELC; o += 512) {
        int b = o / EVAL_RELC, r = o % EVAL_RELC;
        float s = br[r];
        for (int k = 0; k < 128; k++)
            s += sx[b * 128 + k] * Wr[k * EVAL_RELC + r];
        out[o] = s;
    }
}

extern "C" void kernel_launch(void* const* d_in, const int* in_sizes, int n_in,
                              void* d_out, int out_size, void* d_ws,
                              size_t ws_size, hipStream_t stream)
{
    const int* head = (const int*)d_in[0];
    const int* tail = (const int*)d_in[1];
    const int* eh = (const int*)d_in[2];
    const int* et = (const int*)d_in[3];
    const int* er = (const int*)d_in[4];
    const float* ew = (const float*)d_in[5];
    const float* ent_emb = (const float*)d_in[6];
    const float* rel_embs = (const float*)d_in[7];
    const float* Wlin = (const float*)d_in[8];
    const float* blin = (const float*)d_in[9];
    const float* Wrel = (const float*)d_in[10];
    const float* brel = (const float*)d_in[11];
    const float* Watt = (const float*)d_in[12];
    const float* batt = (const float*)d_in[13];
    const float* Wr = (const float*)d_in[14];
    const float* br = (const float*)d_in[15];
    float* out = (float*)d_out;
    float* ws = (float*)d_ws;

    // ---- workspace carve (~7.8 MB; hidB + hidC eliminated) ----
    int4* recs = (int4*)ws;                           // [4][NE] int4
    int* counts = (int*)(recs + (size_t)4 * NE);      // [NSCAN][4]
    float* relwG = (float*)(counts + 4 * NSCAN);      // 2*BB*ALL_RELC floats
    float* qaccB = relwG + 2 * BB * ALL_RELC;         // [2][16][512]
    int* done = (int*)(qaccB + (size_t)2 * BB * ROW); // 1 int

    k_scan<<<NSCAN, 512, 0, stream>>>(head, tail, eh, et, er, ew, ent_emb,
                                      Wrel, brel, Watt, batt,
                                      recs, counts, relwG, qaccB, done);
    k_gather<<<NSCAN, 512, 0, stream>>>(head, tail, ent_emb, rel_embs,
                                        Wlin, blin, Wr, br, recs, counts,
                                        relwG, qaccB, done, out);
}